// Round 1
// 232.783 us; speedup vs baseline: 1.0773x; 1.0773x over previous
//
#include <hip/hip_runtime.h>

#define NBINS 30
#define NCELL 900            // 30*30
#define HWORDS (16*NCELL)    // 14400 cells per matrix histogram set
#define PWORDS (HWORDS/2)    // 7200 packed u32 (2 x u16 cells) per matrix
#define G_MM  2048           // k_minmax grid: 2048 blk x 4 waves = 32 waves/CU
#define NCH   512            // k_hist chunks per matrix (packed slot count)
#define CG    8              // copy-groups for two-stage slot merge

typedef unsigned int u32;

// ws u32 layout:
//  [0] ymin (f32)  [1] ymax (f32)
//  [2..17] umin  [18..33] smin  [34..49] umax  [50..65] smax   (plain f32)
//  [68..69] double lpt_sum   [70..71] double mi2d_sum
//  [72..73] double mi_us_sum [74] finalize counter
//  [PB_OFF .. PB_OFF+68*G_MM)   : k_minmax partials, value-major pb[v*G_MM + b]
//  [HS_OFF .. HS_OFF+2*HWORDS)  : summed histograms {u,s} (fallback path only)
//  [GH_OFF ..]                  : hist slots: packed NCH x {u:7200, s:7200}
//                                 or fallback unpacked copies x {u:14400, s:14400}
//  packed mode only: [PT_OFF ..] : stage-1 partials CG x 28800 u32
#define PB_OFF 128
#define HS_OFF (PB_OFF + 68*G_MM)
#define GH_OFF (HS_OFF + 2*HWORDS)
#define PT_WORDS (CG * 2 * HWORDS / 2 * 2)   // CG * 28800

// fallback-only: zero unpacked histogram copies
__global__ void k_init(u32* W, int zero_words) {
    size_t g = (size_t)blockIdx.x * blockDim.x + threadIdx.x;
    size_t stride = (size_t)gridDim.x * blockDim.x;
    for (size_t i = g; i < (size_t)zero_words; i += stride) W[GH_OFF + i] = 0u;
}

// ---------- pass 1: per-column min/max + y min/max + L_PT (NO atomics) ----------
// Block-contiguous chunks, separate u/s passes, 2-stage rotated prefetch
// (8 x 16B loads outstanding in steady state).
__global__ __launch_bounds__(256) void k_minmax(
    const float* __restrict__ yt, const float* __restrict__ yp,
    const float* __restrict__ uv, const float* __restrict__ sv,
    int N, float* __restrict__ pb)
{
    const float INF = __builtin_inff();
    float umn[4], umx[4], smn[4], smx[4];
#pragma unroll
    for (int k = 0; k < 4; k++) { umn[k] = INF; umx[k] = -INF; smn[k] = INF; smx[k] = -INF; }

    const int t = threadIdx.x;
    const int G = gridDim.x;
    size_t nv4 = (size_t)N * 4;  // 16 floats/row => 4 float4 per row
    // per-block contiguous chunk, multiple of 256 float4
    size_t per = ((nv4 + (size_t)G * 256 - 1) / ((size_t)G * 256)) * 256;
    size_t beg = (size_t)blockIdx.x * per;
    size_t end = beg + per; if (end > nv4) end = nv4;
    const float4* u4 = (const float4*)uv;
    const float4* s4 = (const float4*)sv;

    auto accU = [&](float4 a) {
        umn[0] = fminf(umn[0], a.x); umx[0] = fmaxf(umx[0], a.x);
        umn[1] = fminf(umn[1], a.y); umx[1] = fmaxf(umx[1], a.y);
        umn[2] = fminf(umn[2], a.z); umx[2] = fmaxf(umx[2], a.z);
        umn[3] = fminf(umn[3], a.w); umx[3] = fmaxf(umx[3], a.w);
    };
    auto accS = [&](float4 b) {
        smn[0] = fminf(smn[0], b.x); smx[0] = fmaxf(smx[0], b.x);
        smn[1] = fminf(smn[1], b.y); smx[1] = fmaxf(smx[1], b.y);
        smn[2] = fminf(smn[2], b.z); smx[2] = fmaxf(smx[2], b.z);
        smn[3] = fminf(smn[3], b.w); smx[3] = fmaxf(smx[3], b.w);
    };

    // ---- y phase (6% of traffic): grid-stride, done first ----
    float ymn = INF, ymx = -INF, lpt = 0.0f;
    {
        size_t n4 = (size_t)N >> 2;
        size_t ystr = (size_t)G * 256;
        const float4* yp4 = (const float4*)yp;
        const float4* yt4 = (const float4*)yt;
        for (size_t q = (size_t)blockIdx.x * 256 + t; q < n4; q += ystr) {
            float4 a = yp4[q], b = yt4[q];
            ymn = fminf(ymn, fminf(fminf(a.x, a.y), fminf(a.z, a.w)));
            ymx = fmaxf(ymx, fmaxf(fmaxf(a.x, a.y), fmaxf(a.z, a.w)));
            lpt += fabsf(b.x - a.x) + fabsf(b.y - a.y) + fabsf(b.z - a.z) + fabsf(b.w - a.w);
        }
        for (size_t q = (n4 << 2) + (size_t)blockIdx.x * 256 + t; q < (size_t)N; q += ystr) {
            float y = yp[q];
            ymn = fminf(ymn, y); ymx = fmaxf(ymx, y);
            lpt += fabsf(yt[q] - y);
        }
    }

    // ---- u pass: 4-wide rotated prefetch ----
    {
        size_t i = beg + t;
        if (i + 768 < end) {
            float4 r0 = u4[i], r1 = u4[i + 256], r2 = u4[i + 512], r3 = u4[i + 768];
            i += 1024;
            for (; i + 768 < end; i += 1024) {
                float4 n0 = u4[i], n1 = u4[i + 256], n2 = u4[i + 512], n3 = u4[i + 768];
                accU(r0); accU(r1); accU(r2); accU(r3);
                r0 = n0; r1 = n1; r2 = n2; r3 = n3;
            }
            accU(r0); accU(r1); accU(r2); accU(r3);
        }
        for (; i < end; i += 256) accU(u4[i]);
    }
    // ---- s pass ----
    {
        size_t i = beg + t;
        if (i + 768 < end) {
            float4 r0 = s4[i], r1 = s4[i + 256], r2 = s4[i + 512], r3 = s4[i + 768];
            i += 1024;
            for (; i + 768 < end; i += 1024) {
                float4 n0 = s4[i], n1 = s4[i + 256], n2 = s4[i + 512], n3 = s4[i + 768];
                accS(r0); accS(r1); accS(r2); accS(r3);
                r0 = n0; r1 = n1; r2 = n2; r3 = n3;
            }
            accS(r0); accS(r1); accS(r2); accS(r3);
        }
        for (; i < end; i += 256) accS(s4[i]);
    }

    // wave reduce: column classes keyed by lane&3 (beg is a multiple of 256,
    // step is 256, so class = t&3 exactly as before)
#pragma unroll
    for (int m = 4; m < 64; m <<= 1) {
#pragma unroll
        for (int k = 0; k < 4; k++) {
            umn[k] = fminf(umn[k], __shfl_xor(umn[k], m));
            umx[k] = fmaxf(umx[k], __shfl_xor(umx[k], m));
            smn[k] = fminf(smn[k], __shfl_xor(smn[k], m));
            smx[k] = fmaxf(smx[k], __shfl_xor(smx[k], m));
        }
    }
#pragma unroll
    for (int m = 1; m < 64; m <<= 1) {
        ymn = fminf(ymn, __shfl_xor(ymn, m));
        ymx = fmaxf(ymx, __shfl_xor(ymx, m));
        lpt += __shfl_xor(lpt, m);
    }

    __shared__ float LUmn[64], LUmx[64], LSmn[64], LSmx[64];
    __shared__ float LY[4][3];
    int wave = threadIdx.x >> 6, lane = threadIdx.x & 63;
    if (lane < 4) {
#pragma unroll
        for (int k = 0; k < 4; k++) {
            LUmn[wave * 16 + lane * 4 + k] = umn[k];
            LUmx[wave * 16 + lane * 4 + k] = umx[k];
            LSmn[wave * 16 + lane * 4 + k] = smn[k];
            LSmx[wave * 16 + lane * 4 + k] = smx[k];
        }
    }
    if (lane == 0) { LY[wave][0] = ymn; LY[wave][1] = ymx; LY[wave][2] = lpt; }
    __syncthreads();
    int bid = blockIdx.x;
    if (threadIdx.x < 16) {
        int v = threadIdx.x;
        pb[(size_t)v * G + bid] =
            fminf(fminf(LUmn[v], LUmn[16 + v]), fminf(LUmn[32 + v], LUmn[48 + v]));
        pb[(size_t)(16 + v) * G + bid] =
            fminf(fminf(LSmn[v], LSmn[16 + v]), fminf(LSmn[32 + v], LSmn[48 + v]));
        pb[(size_t)(32 + v) * G + bid] =
            fmaxf(fmaxf(LUmx[v], LUmx[16 + v]), fmaxf(LUmx[32 + v], LUmx[48 + v]));
        pb[(size_t)(48 + v) * G + bid] =
            fmaxf(fmaxf(LSmx[v], LSmx[16 + v]), fmaxf(LSmx[32 + v], LSmx[48 + v]));
    } else if (threadIdx.x == 64) {
        pb[(size_t)64 * G + bid] = fminf(fminf(LY[0][0], LY[1][0]), fminf(LY[2][0], LY[3][0]));
        pb[(size_t)65 * G + bid] = fmaxf(fmaxf(LY[0][1], LY[1][1]), fmaxf(LY[2][1], LY[3][1]));
        pb[(size_t)66 * G + bid] = LY[0][2] + LY[1][2] + LY[2][2] + LY[3][2];
    }
}

// ---------- collapse partials -> W (67 blocks); also zero accumulators ----------
__global__ __launch_bounds__(256) void k_reduce(const float* __restrict__ pb, int G, u32* W) {
    if (blockIdx.x == 0 && threadIdx.x == 0) {
        ((double*)(W + 70))[0] = 0.0;   // mi2d accumulator
        ((double*)(W + 72))[0] = 0.0;   // mi_us accumulator
        W[74] = 0u;                     // finalize counter
    }
    const float INF = __builtin_inff();
    int v = blockIdx.x;                      // 0..66
    const float* src = pb + (size_t)v * G;
    int op = (v == 66) ? 2 : ((v < 32 || v == 64) ? 0 : 1);   // 0=min 1=max 2=sum
    float acc = (op == 0) ? INF : -INF;
    double da = 0.0;
    for (int b = threadIdx.x; b < G; b += 256) {
        float x = src[b];
        if (op == 0) acc = fminf(acc, x);
        else if (op == 1) acc = fmaxf(acc, x);
        else da += (double)x;
    }
#pragma unroll
    for (int m = 1; m < 64; m <<= 1) {
        float o = __shfl_xor(acc, m);
        acc = (op == 0) ? fminf(acc, o) : fmaxf(acc, o);
        da += __shfl_xor(da, m);
    }
    __shared__ float sf[4];
    __shared__ double sd[4];
    int wave = threadIdx.x >> 6;
    if ((threadIdx.x & 63) == 0) { sf[wave] = acc; sd[wave] = da; }
    __syncthreads();
    if (threadIdx.x == 0) {
        float r = (op == 0) ? fminf(fminf(sf[0], sf[1]), fminf(sf[2], sf[3]))
                            : fmaxf(fmaxf(sf[0], sf[1]), fmaxf(sf[2], sf[3]));
        if (v == 66)      ((double*)(W + 68))[0] = sd[0] + sd[1] + sd[2] + sd[3];
        else if (v == 64) ((float*)W)[0] = r;
        else if (v == 65) ((float*)W)[1] = r;
        else              ((float*)W)[2 + v] = r;
    }
}

// ---------- pass 2: 2-D histograms, u16-packed LDS, np.histogram-exact binning ----------
__global__ __launch_bounds__(512) void k_hist(
    const float* __restrict__ yp, const float* __restrict__ uv, const float* __restrict__ sv,
    int N, const u32* __restrict__ W, u32* __restrict__ gh, int copies)
{
    __shared__ u32 hist[PWORDS];   // 14400 u16 cells packed into 7200 u32
    __shared__ float ex[16][32];   // 31 edges per col (+pad)
    __shared__ float ey[32];
    __shared__ float emn[16], esc[16];
    __shared__ float yp0[2];       // ymn, ysc
    int mat = blockIdx.y;
    const float* src = mat ? sv : uv;
    const float* Wf = (const float*)W;

    for (int i = threadIdx.x; i < PWORDS; i += 512) hist[i] = 0;
    if (threadIdx.x < 16) {
        int j = threadIdx.x;
        float mn = Wf[2 + mat * 16 + j];
        float mx = Wf[34 + mat * 16 + j];
        float step = (mx - mn) / 30.0f;
        for (int m = 0; m < 31; m++) ex[j][m] = __fadd_rn(__fmul_rn((float)m, step), mn);
        ex[j][30] = mx;            // np.linspace endpoint
        emn[j] = mn;
        esc[j] = (mx > mn) ? 30.0f / (mx - mn) : 0.0f;
    } else if (threadIdx.x == 16) {
        float mn = Wf[0], mx = Wf[1];
        float step = (mx - mn) / 30.0f;
        for (int m = 0; m < 31; m++) ey[m] = __fadd_rn(__fmul_rn((float)m, step), mn);
        ey[30] = mx;
        yp0[0] = mn;
        yp0[1] = (mx > mn) ? 30.0f / (mx - mn) : 0.0f;
    }
    __syncthreads();

    float ymn = yp0[0], ysc = yp0[1];
    int rpb = (N + gridDim.x - 1) / gridDim.x;
    int r0 = blockIdx.x * rpb;
    int r1 = r0 + rpb; if (r1 > N) r1 = N;
    for (int row = r0 + threadIdx.x; row < r1; row += 512) {
        float y = yp[row];
        int yb = (int)__fmul_rn(__fsub_rn(y, ymn), ysc);
        if (yb > 29) yb = 29;
        if (y < ey[yb]) yb--;
        if (yb != 29 && y >= ey[yb + 1]) yb++;

        const float4* p = (const float4*)(src + (size_t)row * 16);
        float4 q0 = p[0], q1 = p[1], q2 = p[2], q3 = p[3];
        float v[16] = {q0.x, q0.y, q0.z, q0.w, q1.x, q1.y, q1.z, q1.w,
                       q2.x, q2.y, q2.z, q2.w, q3.x, q3.y, q3.z, q3.w};
#pragma unroll
        for (int j = 0; j < 16; j++) {
            float vv = v[j];
            int b = (int)__fmul_rn(__fsub_rn(vv, emn[j]), esc[j]);
            if (b > 29) b = 29;
            if (vv < ex[j][b]) b--;
            if (b != 29 && vv >= ex[j][b + 1]) b++;
            u32 idx = (u32)(j * NCELL + b * NBINS + yb);
            atomicAdd(&hist[idx >> 1], 1u << ((idx & 1) * 16));
        }
    }
    __syncthreads();

    if (copies == (int)gridDim.x) {
        // packed private slot: plain coalesced stores, no atomics
        u32* dst = gh + ((size_t)blockIdx.x * 2 + mat) * PWORDS;
        for (int i = threadIdx.x; i < PWORDS; i += 512) dst[i] = hist[i];
    } else {
        // fallback: unpack and atomically accumulate into unpacked copies
        u32* dst = gh + (((size_t)(blockIdx.x % copies)) * 2 + mat) * HWORDS;
        for (int i = threadIdx.x; i < PWORDS; i += 512) {
            u32 w = hist[i];
            u32 lo = w & 0xFFFFu, hi = w >> 16;
            if (lo) atomicAdd(&dst[2 * i], lo);
            if (hi) atomicAdd(&dst[2 * i + 1], hi);
        }
    }
}

// ---------- stage 1: sum 64 slots per copy-group (packed path) ----------
__global__ __launch_bounds__(256) void k_sum1(
    const u32* __restrict__ gh, u32* __restrict__ part, int slots_per_cg)
{
    int f = blockIdx.x * 256 + threadIdx.x;
    if (f >= 2 * PWORDS) return;
    int cg = blockIdx.y;
    const u32* p = gh + (size_t)(cg * slots_per_cg) * (2 * PWORDS) + f;
    u32 lo0 = 0, hi0 = 0, lo1 = 0, hi1 = 0;
    int s = 0;
    for (; s + 3 < slots_per_cg; s += 4) {
        u32 w0 = p[(size_t)s * (2 * PWORDS)];
        u32 w1 = p[(size_t)(s + 1) * (2 * PWORDS)];
        u32 w2 = p[(size_t)(s + 2) * (2 * PWORDS)];
        u32 w3 = p[(size_t)(s + 3) * (2 * PWORDS)];
        lo0 += w0 & 0xFFFFu; hi0 += w0 >> 16;
        lo1 += w1 & 0xFFFFu; hi1 += w1 >> 16;
        lo0 += w2 & 0xFFFFu; hi0 += w2 >> 16;
        lo1 += w3 & 0xFFFFu; hi1 += w3 >> 16;
    }
    for (; s < slots_per_cg; s++) {
        u32 w = p[(size_t)s * (2 * PWORDS)];
        lo0 += w & 0xFFFFu; hi0 += w >> 16;
    }
    int mat = f / PWORDS, i = f - mat * PWORDS;
    u32* dst = part + (size_t)cg * (2 * HWORDS) + (size_t)mat * HWORDS + 2 * i;
    dst[0] = lo0 + lo1;
    dst[1] = hi0 + hi1;
}

// ---------- fallback merge (unpacked copies <= 8) ----------
__global__ __launch_bounds__(256) void k_sum(
    const u32* __restrict__ gh, u32* __restrict__ hs, int copies)
{
    int f = blockIdx.x * 256 + threadIdx.x;
    if (f >= 2 * HWORDS) return;
    u32 a = 0;
    const u32* p = gh + f;
    for (int s = 0; s < copies; s++) a += p[(size_t)s * (2 * HWORDS)];
    hs[f] = a;
}

// ---------- fused: stage-2 sum + per-histogram MI + mi_us + final combine ----------
// blocks 0..31: one histogram each (sums CG partials inline in packed mode)
// block 32:     mi_us on first 16 rows
// last block to finish writes the output (threadfence + atomic counter).
__global__ __launch_bounds__(256) void k_mi_final(
    const u32* __restrict__ part, const u32* __restrict__ hs, int packed,
    const float* __restrict__ uv, const float* __restrict__ sv,
    int N, u32* W, float* out)
{
    int h = blockIdx.x;
    if (h < 32) {
        __shared__ float C[NCELL];
        __shared__ float rsums[NBINS], csums[NBINS];
        __shared__ double red[4];
        int mat = h >> 4, col = h & 15;
        if (packed) {
            const u32* src = part + (size_t)mat * HWORDS + (size_t)col * NCELL;
            for (int c = threadIdx.x; c < NCELL; c += 256) {
                u32 a = 0;
#pragma unroll
                for (int cg = 0; cg < CG; cg++) a += src[(size_t)cg * (2 * HWORDS) + c];
                C[c] = (float)a;
            }
        } else {
            const u32* src = hs + (size_t)mat * HWORDS + (size_t)col * NCELL;
            for (int c = threadIdx.x; c < NCELL; c += 256) C[c] = (float)src[c];
        }
        __syncthreads();
        if (threadIdx.x < NBINS) {
            float s = 0;
            for (int j = 0; j < NBINS; j++) s += C[threadIdx.x * NBINS + j];
            rsums[threadIdx.x] = s;
        } else if (threadIdx.x >= 32 && threadIdx.x < 32 + NBINS) {
            int j = threadIdx.x - 32;
            float s = 0;
            for (int i = 0; i < NBINS; i++) s += C[i * NBINS + j];
            csums[j] = s;
        }
        __syncthreads();

        const float n = (float)N;
        double acc = 0.0;
        for (int c = threadIdx.x; c < NCELL; c += 256) {
            int i = c / NBINS, j = c % NBINS;
            float pxy = (C[c] > 0.0f) ? (C[c] / n) : 1e-10f;
            float px  = (rsums[i] > 0.0f) ? (rsums[i] / n) : 1e-10f;
            float py  = (csums[j] > 0.0f) ? (csums[j] / n) : 1e-10f;
            acc += (double)(pxy * logf(pxy / (px * py)));
        }
#pragma unroll
        for (int o = 32; o > 0; o >>= 1) acc += __shfl_xor(acc, o);
        int wid = threadIdx.x >> 6;
        if ((threadIdx.x & 63) == 0) red[wid] = acc;
        __syncthreads();
        if (threadIdx.x == 0) {
            double tt = red[0] + red[1] + red[2] + red[3];
            atomicAdd((double*)(W + 70), tt);
        }
    } else {
        // mi_us on first 16 rows of uv/sv
        __shared__ double mis[16];
        int t = threadIdx.x;
        if (t < 16) {
            float uval[16], sval[16];
#pragma unroll
            for (int k = 0; k < 16; k++) { uval[k] = uv[t * 16 + k]; sval[k] = sv[t * 16 + k]; }
            float umn = uval[0], umx = uval[0], smn = sval[0], smx = sval[0];
#pragma unroll
            for (int k = 1; k < 16; k++) {
                umn = fminf(umn, uval[k]); umx = fmaxf(umx, uval[k]);
                smn = fminf(smn, sval[k]); smx = fmaxf(smx, sval[k]);
            }
            float ue[30], se[30];
            float ustep = (umx - umn) / 29.0f, sstep = (smx - smn) / 29.0f;
            for (int m = 0; m < 30; m++) {
                ue[m] = __fadd_rn(__fmul_rn((float)m, ustep), umn);
                se[m] = __fadd_rn(__fmul_rn((float)m, sstep), smn);
            }
            ue[29] = umx; se[29] = smx;
            int lu[16], ls[16];
#pragma unroll
            for (int k = 0; k < 16; k++) {
                int c = 0, c2 = 0;
                for (int m = 0; m < 30; m++) {
                    c  += (ue[m] <= uval[k]) ? 1 : 0;
                    c2 += (se[m] <= sval[k]) ? 1 : 0;
                }
                lu[k] = c; ls[k] = c2;
            }
            double mi = 0.0;
#pragma unroll
            for (int k = 0; k < 16; k++) {
                int cu = 0, cs2 = 0, cc = 0;
#pragma unroll
                for (int j = 0; j < 16; j++) {
                    int bu = (lu[j] == lu[k]) ? 1 : 0;
                    int bs = (ls[j] == ls[k]) ? 1 : 0;
                    cu += bu; cs2 += bs; cc += (bu & bs);
                }
                mi += log((double)(cc * 16) / ((double)cu * (double)cs2));
            }
            mis[t] = mi / 16.0;
        }
        __syncthreads();
        if (t == 0) {
            double mu = 0.0;
            for (int i = 0; i < 16; i++) mu += mis[i];
            atomicAdd((double*)(W + 72), mu);
        }
    }

    // finalize: last of the 33 blocks combines and writes the scalar output
    __syncthreads();
    if (threadIdx.x == 0) {
        __threadfence();
        u32 old = atomicAdd(W + 74, 1u);
        if (old == 32u) {
            double mi2 = atomicAdd((double*)(W + 70), 0.0);
            double mus = atomicAdd((double*)(W + 72), 0.0);
            double lpt = ((const double*)(W + 68))[0] / (double)N;
            out[0] = (float)(lpt + 0.1 * mi2 - 0.05 * mus);
        }
    }
}

extern "C" void kernel_launch(void* const* d_in, const int* in_sizes, int n_in,
                              void* d_out, int out_size, void* d_ws, size_t ws_size,
                              hipStream_t stream)
{
    int N = in_sizes[0];
    const float* yt = (const float*)d_in[0];
    const float* yp = (const float*)d_in[1];
    const float* uv = (const float*)d_in[4];
    const float* sv = (const float*)d_in[5];
    u32* W = (u32*)d_ws;
    float* pb = (float*)(W + PB_OFF);
    u32* hs = W + HS_OFF;
    u32* gh = W + GH_OFF;

    // packed mode needs slots + stage-1 partials
    size_t slots_words = (size_t)NCH * 2 * PWORDS;        // 7.37M words
    size_t part_words  = (size_t)CG * 2 * HWORDS;         // 230400 words
    size_t avail_words = (ws_size / 4 > (size_t)GH_OFF) ? ws_size / 4 - GH_OFF : 0;
    int copies, zero_words, packed;
    if (avail_words >= slots_words + part_words) {
        copies = NCH; packed = 1; zero_words = 0;
    } else {
        long c = (long)(avail_words / (2 * HWORDS));
        copies = (c < 1) ? 1 : ((c > 8) ? 8 : (int)c);
        packed = 0;
        zero_words = copies * 2 * HWORDS;
    }
    u32* part = gh + slots_words;

    if (!packed)
        k_init<<<dim3(120), dim3(512), 0, stream>>>(W, zero_words);
    k_minmax<<<dim3(G_MM), dim3(256), 0, stream>>>(yt, yp, uv, sv, N, pb);
    k_reduce<<<dim3(67), dim3(256), 0, stream>>>(pb, G_MM, W);
    k_hist<<<dim3(NCH, 2), dim3(512), 0, stream>>>(yp, uv, sv, N, W, gh, copies);
    if (packed) {
        k_sum1<<<dim3((2 * PWORDS + 255) / 256, CG), dim3(256), 0, stream>>>(gh, part, NCH / CG);
    } else {
        k_sum<<<dim3((2 * HWORDS + 255) / 256), dim3(256), 0, stream>>>(gh, hs, copies);
    }
    k_mi_final<<<dim3(33), dim3(256), 0, stream>>>(part, hs, packed, uv, sv, N, W, (float*)d_out);
}